// Round 1
// baseline (405.753 us; speedup 1.0000x reference)
//
#include <hip/hip_runtime.h>

// Quantized (int4-packed) embedding bag, sum mode, output [B, 3*D] = [eb|eb|other].
// V=1e6, D=128, B=16384, L=50. weights: [V, D/2] int32 (one byte/elem, two nibbles).
// One wave per bag; lane owns packed dword `lane` -> output cols 2*lane, 2*lane+1.

#define DIM 128
#define DWORDS_PER_ROW (DIM / 2)  // 64 packed dwords per row

__global__ __launch_bounds__(256) void qebag_kernel(
    const unsigned* __restrict__ weights,   // [V, 64] packed
    const float* __restrict__ scales,       // [V]
    const float* __restrict__ zeros,        // [V]
    const int* __restrict__ indices,        // [N]
    const int* __restrict__ offsets,        // [B+1]
    const float* __restrict__ other,        // [B, 128]
    float* __restrict__ out,                // [B, 384]
    int B) {
  const int wave = threadIdx.x >> 6;
  const int lane = threadIdx.x & 63;
  int bag = blockIdx.x * 4 + wave;
  if (bag >= B) return;
  // Wave-uniform bag index -> scalar loads for indices/scales/zeros.
  bag = __builtin_amdgcn_readfirstlane(bag);

  const int start = offsets[bag];
  const int end   = offsets[bag + 1];

  float acc_lo = 0.f, acc_hi = 0.f, corr = 0.f;  // corr = sum(s*z), per-bag scalar

  for (int j = start; j < end; ++j) {
    const int idx = indices[j];           // uniform -> s_load
    const float s = scales[idx];          // uniform -> s_load
    const float z = zeros[idx];           // uniform -> s_load
    const unsigned w = weights[(size_t)idx * DWORDS_PER_ROW + lane];  // coalesced 256B/wave
    acc_lo = fmaf(s, (float)(w & 0xFu), acc_lo);
    acc_hi = fmaf(s, (float)((w >> 4) & 0xFu), acc_hi);
    corr   = fmaf(s, z, corr);
  }

  const float2 e = make_float2(acc_lo - corr, acc_hi - corr);
  float2* orow = (float2*)(out + (size_t)bag * (3 * DIM));
  const float2* oth = (const float2*)(other + (size_t)bag * DIM);
  orow[lane]       = e;            // cols [0,128)
  orow[64 + lane]  = e;            // cols [128,256) (eb duplicated)
  orow[128 + lane] = oth[lane];    // cols [256,384) passthrough
}

extern "C" void kernel_launch(void* const* d_in, const int* in_sizes, int n_in,
                              void* d_out, int out_size, void* d_ws, size_t ws_size,
                              hipStream_t stream) {
  const unsigned* weights = (const unsigned*)d_in[0];
  const float* scales     = (const float*)d_in[1];
  const float* zeros      = (const float*)d_in[2];
  const int* indices      = (const int*)d_in[3];
  const int* offsets      = (const int*)d_in[4];
  const float* other      = (const float*)d_in[5];
  float* out              = (float*)d_out;

  const int B = in_sizes[5] / DIM;         // other_tensor is [B, 128]
  const int blocks = (B + 3) / 4;          // 4 waves (bags) per 256-thread block

  qebag_kernel<<<blocks, 256, 0, stream>>>(weights, scales, zeros, indices,
                                           offsets, other, out, B);
}

// Round 2
// 380.088 us; speedup vs baseline: 1.0675x; 1.0675x over previous
//
#include <hip/hip_runtime.h>

// Quantized (int4-packed) embedding bag, sum mode, output [B, 3*D] = [eb|eb|other].
// V=1e6, D=128, B=16384, L=50. weights: [V, D/2] int32 (one byte/elem, two nibbles).
// One wave per bag; lane owns packed dword `lane` -> output cols 2*lane, 2*lane+1.
//
// R2: metadata (idx, scale, scale*zero) gathered in a PARALLEL vector phase
// (lane j owns bag-row j), then broadcast per-iteration via v_readlane.
// K-loop contains only the coalesced 256B weight gather -> pipelinable.

#define DIM 128
#define DPR 64  // packed dwords per row

__global__ __launch_bounds__(256) void qebag_kernel(
    const unsigned* __restrict__ weights,   // [V, 64]
    const float* __restrict__ scales,       // [V]
    const float* __restrict__ zeros,        // [V]
    const int* __restrict__ indices,        // [N]
    const int* __restrict__ offsets,        // [B+1]
    const float* __restrict__ other,        // [B, 128]
    float* __restrict__ out,                // [B, 384]
    int B) {
  const int wave = threadIdx.x >> 6;
  const int lane = threadIdx.x & 63;
  int bag = blockIdx.x * 4 + wave;
  if (bag >= B) return;
  bag = __builtin_amdgcn_readfirstlane(bag);  // uniform -> s_load for offsets

  const int start = offsets[bag];
  const int count = offsets[bag + 1] - start;  // wave-uniform (50)

  float acc_lo = 0.f, acc_hi = 0.f, corr = 0.f;

  for (int base = 0; base < count; base += 64) {
    const int cnt = min(64, count - base);

    // ---- parallel metadata gather: lane j -> bag row (base + j) ----
    int idx = 0;
    float s = 0.f, sz = 0.f;
    if (lane < cnt) {
      idx = indices[start + base + lane];   // coalesced vector load
      s = scales[idx];                      // parallel vector gather
      sz = s * zeros[idx];                  // parallel vector gather
    }
    // corr += sum_j s_j*z_j (butterfly, result in all lanes)
    float c = sz;
    #pragma unroll
    for (int off = 1; off < 64; off <<= 1) c += __shfl_xor(c, off);
    corr += c;

    // ---- weight gather loop: only memory op is the 256B/wave row load ----
    #pragma unroll 5
    for (int j = 0; j < cnt; ++j) {
      const int ij = __builtin_amdgcn_readlane(idx, j);        // SGPR broadcast
      const float sj =
          __uint_as_float(__builtin_amdgcn_readlane(__float_as_uint(s), j));
      const unsigned w = weights[(size_t)ij * DPR + lane];     // coalesced 256B
      acc_lo = fmaf(sj, (float)(w & 0xFu), acc_lo);
      acc_hi = fmaf(sj, (float)((w >> 4) & 0xFu), acc_hi);
    }
  }

  const float2 e = make_float2(acc_lo - corr, acc_hi - corr);
  float2* orow = (float2*)(out + (size_t)bag * (3 * DIM));
  const float2* oth = (const float2*)(other + (size_t)bag * DIM);
  orow[lane]       = e;            // cols [0,128)
  orow[64 + lane]  = e;            // cols [128,256) (eb duplicated)
  orow[128 + lane] = oth[lane];    // cols [256,384) passthrough
}

extern "C" void kernel_launch(void* const* d_in, const int* in_sizes, int n_in,
                              void* d_out, int out_size, void* d_ws, size_t ws_size,
                              hipStream_t stream) {
  const unsigned* weights = (const unsigned*)d_in[0];
  const float* scales     = (const float*)d_in[1];
  const float* zeros      = (const float*)d_in[2];
  const int* indices      = (const int*)d_in[3];
  const int* offsets      = (const int*)d_in[4];
  const float* other      = (const float*)d_in[5];
  float* out              = (float*)d_out;

  const int B = in_sizes[5] / DIM;   // other_tensor is [B, 128]
  const int blocks = (B + 3) / 4;    // 4 waves (bags) per 256-thread block

  qebag_kernel<<<blocks, 256, 0, stream>>>(weights, scales, zeros, indices,
                                           offsets, other, out, B);
}

// Round 3
// 356.887 us; speedup vs baseline: 1.1369x; 1.0650x over previous
//
#include <hip/hip_runtime.h>

// Quantized (int4-packed) embedding bag, sum mode, output [B, 3*D] = [eb|eb|other].
// V=1e6, D=128, B=16384, L=50. weights: [V, D/2] int32 (one byte/elem, two nibbles).
//
// R3: one wave per bag, FOUR rows per load instruction:
//   lane l -> group g = l>>4 (row j+g), sub t = l&15 (dwords 4t..4t+3 = cols 8t..8t+7)
//   -> one global_load_dwordx4 fetches 1KB across 4 rows; per-row idx/scale via
//   ds_bpermute (__shfl). 4x fewer VMEM instrs, ~16 rows in flight per wave.

#define DIM 128

__global__ __launch_bounds__(256) void qebag_kernel(
    const uint4* __restrict__ weights,      // [V, 16] viewed as uint4
    const float* __restrict__ scales,       // [V]
    const float* __restrict__ zeros,        // [V]
    const int* __restrict__ indices,        // [N]
    const int* __restrict__ offsets,        // [B+1]
    const float* __restrict__ other,        // [B, 128]
    float* __restrict__ out,                // [B, 384]
    int B) {
  const int wave = threadIdx.x >> 6;
  const int lane = threadIdx.x & 63;
  const int g = lane >> 4;   // row-group 0..3
  const int t = lane & 15;   // sublane -> cols [8t, 8t+8)
  int bag = blockIdx.x * 4 + wave;
  if (bag >= B) return;
  bag = __builtin_amdgcn_readfirstlane(bag);  // uniform -> s_load for offsets

  const int start = offsets[bag];
  const int count = offsets[bag + 1] - start;  // 50 here, keep generic

  float acc[8];
  #pragma unroll
  for (int k = 0; k < 8; ++k) acc[k] = 0.f;
  float corr = 0.f;  // sum(s*z) over the bag (scalar, same for all cols)

  for (int base = 0; base < count; base += 64) {
    const int cnt = min(64, count - base);

    // parallel metadata gather: lane j owns bag-row (base+j)
    int idx = 0; float s = 0.f, sz = 0.f;
    if (lane < cnt) {
      idx = indices[start + base + lane];   // coalesced
      s = scales[idx];                      // parallel gather (4MB, L2/L3-warm)
      sz = s * zeros[idx];
    }
    float c = sz;                           // butterfly: corr in all lanes
    #pragma unroll
    for (int off = 1; off < 64; off <<= 1) c += __shfl_xor(c, off);
    corr += c;

    const int iters = (cnt + 3) >> 2;       // 4 rows per iteration
    #pragma unroll 4
    for (int i = 0; i < iters; ++i) {
      const int src = 4 * i + g;            // this group's row within chunk
      const int ij = __shfl(idx, src);      // ds_bpermute broadcast
      const float sj = __shfl(s, src);      // (src >= cnt -> idx=0, s=0: no-op row)
      const uint4 w = weights[(size_t)ij * 16 + t];  // 16B/lane, 1KB/wave
      acc[0] = fmaf(sj, (float)(w.x & 0xFu), acc[0]);
      acc[1] = fmaf(sj, (float)((w.x >> 4) & 0xFu), acc[1]);
      acc[2] = fmaf(sj, (float)(w.y & 0xFu), acc[2]);
      acc[3] = fmaf(sj, (float)((w.y >> 4) & 0xFu), acc[3]);
      acc[4] = fmaf(sj, (float)(w.z & 0xFu), acc[4]);
      acc[5] = fmaf(sj, (float)((w.z >> 4) & 0xFu), acc[5]);
      acc[6] = fmaf(sj, (float)(w.w & 0xFu), acc[6]);
      acc[7] = fmaf(sj, (float)((w.w >> 4) & 0xFu), acc[7]);
    }
  }

  // reduce the 4 row-groups (lane bits 4,5); all lanes end with full sums
  #pragma unroll
  for (int k = 0; k < 8; ++k) {
    acc[k] += __shfl_xor(acc[k], 16);
    acc[k] += __shfl_xor(acc[k], 32);
    acc[k] -= corr;
  }

  float4* o4 = (float4*)(out + (size_t)bag * (3 * DIM));
  if (g < 2) {
    // groups 0,1 write the two identical eb blocks (cols [0,128) and [128,256))
    const float4 lo = make_float4(acc[0], acc[1], acc[2], acc[3]);
    const float4 hi = make_float4(acc[4], acc[5], acc[6], acc[7]);
    o4[g * 32 + 2 * t]     = lo;
    o4[g * 32 + 2 * t + 1] = hi;
  } else {
    // groups 2,3 copy other_tensor into cols [256,384)
    const int h = (g - 2) * 16 + t;  // 0..31, float4 units
    const float4* oth = (const float4*)(other + (size_t)bag * DIM);
    o4[64 + h] = oth[h];
  }
}

extern "C" void kernel_launch(void* const* d_in, const int* in_sizes, int n_in,
                              void* d_out, int out_size, void* d_ws, size_t ws_size,
                              hipStream_t stream) {
  const uint4* weights  = (const uint4*)d_in[0];
  const float* scales   = (const float*)d_in[1];
  const float* zeros    = (const float*)d_in[2];
  const int* indices    = (const int*)d_in[3];
  const int* offsets    = (const int*)d_in[4];
  const float* other    = (const float*)d_in[5];
  float* out            = (float*)d_out;

  const int B = in_sizes[5] / DIM;   // other_tensor is [B, 128]
  const int blocks = (B + 3) / 4;    // 4 waves (bags) per 256-thread block

  qebag_kernel<<<blocks, 256, 0, stream>>>(weights, scales, zeros, indices,
                                           offsets, other, out, B);
}

// Round 4
// 349.841 us; speedup vs baseline: 1.1598x; 1.0201x over previous
//
#include <hip/hip_runtime.h>

// Quantized (int4-packed) embedding bag, sum mode, output [B, 3*D] = [eb|eb|other].
// V=1e6, D=128, B=16384, L=50. weights: [V, D/2] int32; each int32 holds ONE byte
// (two nibbles -> 2 output cols). Row = 64 dwords = 256 B.
//
// R4: one wave per bag; full straight-line burst of 16 row-quads:
//   lane l -> group g=l>>4 (row 4i+g), sub t=l&15 (dwords 4t..4t+3 -> cols 8t..8t+7)
//   All 32 shfl broadcasts + 16 global_load_dwordx4 issued before consumption
//   (~16KB in flight per wave) to test the MLP-vs-DRAM-ceiling hypothesis.
//   Lanes >= count are padded (idx=0, s=0) -> branch-free, zero contribution.

#define DIM 128

__global__ __launch_bounds__(256) void qebag_kernel(
    const uint4* __restrict__ weights,      // [V, 16] viewed as uint4
    const float* __restrict__ scales,       // [V]
    const float* __restrict__ zeros,        // [V]
    const int* __restrict__ indices,        // [N]
    const int* __restrict__ offsets,        // [B+1]
    const float* __restrict__ other,        // [B, 128]
    float* __restrict__ out,                // [B, 384]
    int B) {
  const int wave = threadIdx.x >> 6;
  const int lane = threadIdx.x & 63;
  const int g = lane >> 4;   // row-group 0..3
  const int t = lane & 15;   // sublane -> cols [8t, 8t+8)
  int bag = blockIdx.x * 4 + wave;
  if (bag >= B) return;
  bag = __builtin_amdgcn_readfirstlane(bag);  // uniform -> s_load for offsets

  const int start = offsets[bag];
  const int count = offsets[bag + 1] - start;  // 50 here; keep generic

  // Prefetch `other` passthrough early (lanes 32..63 own it in the epilogue);
  // independent load that overlaps the whole gather phase.
  const float4* oth4 = (const float4*)(other + (size_t)bag * DIM);
  float4 oth = make_float4(0.f, 0.f, 0.f, 0.f);
  if (lane >= 32) oth = oth4[lane - 32];

  float acc[8];
  #pragma unroll
  for (int k = 0; k < 8; ++k) acc[k] = 0.f;
  float corr = 0.f;  // sum(s*z) over the bag

  for (int base = 0; base < count; base += 64) {
    const int cnt = min(64, count - base);

    // parallel metadata gather: lane j owns bag-row (base+j); pad beyond cnt
    int idx = 0; float s = 0.f, sz = 0.f;
    if (lane < cnt) {
      idx = indices[start + base + lane];   // coalesced
      s = scales[idx];                      // random gather (L2/L3-warm, off path)
      sz = s * zeros[idx];
    }
    float c = sz;                           // butterfly: corr in all lanes
    #pragma unroll
    for (int off = 1; off < 64; off <<= 1) c += __shfl_xor(c, off);
    corr += c;

    // ---- straight-line burst: 16 quads cover rows 0..63 of this chunk ----
    int ij[16]; float sj[16];
    #pragma unroll
    for (int i = 0; i < 16; ++i) {
      const int src = 4 * i + g;            // padded lanes give idx=0, s=0
      ij[i] = __shfl(idx, src);
      sj[i] = __shfl(s, src);
    }
    uint4 w[16];
    #pragma unroll
    for (int i = 0; i < 16; ++i)
      w[i] = weights[(size_t)(unsigned)ij[i] * 16 + t];  // 1KB/wave each, 16 in flight
    #pragma unroll
    for (int i = 0; i < 16; ++i) {
      acc[0] = fmaf(sj[i], (float)(w[i].x & 0xFu), acc[0]);
      acc[1] = fmaf(sj[i], (float)((w[i].x >> 4) & 0xFu), acc[1]);
      acc[2] = fmaf(sj[i], (float)(w[i].y & 0xFu), acc[2]);
      acc[3] = fmaf(sj[i], (float)((w[i].y >> 4) & 0xFu), acc[3]);
      acc[4] = fmaf(sj[i], (float)(w[i].z & 0xFu), acc[4]);
      acc[5] = fmaf(sj[i], (float)((w[i].z >> 4) & 0xFu), acc[5]);
      acc[6] = fmaf(sj[i], (float)(w[i].w & 0xFu), acc[6]);
      acc[7] = fmaf(sj[i], (float)((w[i].w >> 4) & 0xFu), acc[7]);
    }
  }

  // reduce the 4 row-groups (lane bits 4,5); all lanes end with full sums
  #pragma unroll
  for (int k = 0; k < 8; ++k) {
    acc[k] += __shfl_xor(acc[k], 16);
    acc[k] += __shfl_xor(acc[k], 32);
    acc[k] -= corr;
  }

  float4* o4 = (float4*)(out + (size_t)bag * (3 * DIM));
  if (g < 2) {
    // groups 0,1 write the two identical eb blocks (cols [0,128) and [128,256))
    const float4 lo = make_float4(acc[0], acc[1], acc[2], acc[3]);
    const float4 hi = make_float4(acc[4], acc[5], acc[6], acc[7]);
    o4[g * 32 + 2 * t]     = lo;
    o4[g * 32 + 2 * t + 1] = hi;
  } else {
    // groups 2,3 copy other_tensor into cols [256,384)
    o4[64 + (lane - 32)] = oth;
  }
}

extern "C" void kernel_launch(void* const* d_in, const int* in_sizes, int n_in,
                              void* d_out, int out_size, void* d_ws, size_t ws_size,
                              hipStream_t stream) {
  const uint4* weights  = (const uint4*)d_in[0];
  const float* scales   = (const float*)d_in[1];
  const float* zeros    = (const float*)d_in[2];
  const int* indices    = (const int*)d_in[3];
  const int* offsets    = (const int*)d_in[4];
  const float* other    = (const float*)d_in[5];
  float* out            = (float*)d_out;

  const int B = in_sizes[5] / DIM;   // other_tensor is [B, 128]
  const int blocks = (B + 3) / 4;    // 4 waves (bags) per 256-thread block

  qebag_kernel<<<blocks, 256, 0, stream>>>(weights, scales, zeros, indices,
                                           offsets, other, out, B);
}